// Round 4
// baseline (225.313 us; speedup 1.0000x reference)
//
#include <hip/hip_runtime.h>

// RelativePositionSDPA — R3: max-free flash, 4 blocks/CU (LDS 38.7 KB).
// vs R2: Pb ring f16 [slot][row]; band B-frags direct from global R (Rb gone);
// Ps aliases Kb; fixed-shift softmax p=exp(s-40) (no max reduction, no alpha
// rescale, no swizzles); P,V in bf16 with a ones-column in V accumulating
// l = sum(p) inside the PV MFMA; 3 barriers/iter.
//
// Shift algebra (verified R0 fp32 / R2): col-coord c ≡ e-1-u; ring slot=c&127;
// R row = c mod S; gather pos = Pb[slot][ii+u], zero at e==1.

#define SQ    1024
#define HD    64
#define NHD   16
#define RMAX  2048

typedef _Float16 f16x8 __attribute__((ext_vector_type(8)));
typedef short    b16x8 __attribute__((ext_vector_type(8)));
typedef float    f32x4 __attribute__((ext_vector_type(4)));

#define MFMA_F16(A,B,C)  __builtin_amdgcn_mfma_f32_16x16x32_f16((A),(B),(C),0,0,0)
#define MFMA_BF16(A,B,C) __builtin_amdgcn_mfma_f32_16x16x32_bf16((A),(B),(C),0,0,0)

__device__ __forceinline__ short f2b(float f) {          // fp32 -> bf16 RTN-even
  unsigned u = __builtin_bit_cast(unsigned, f);
  u += 0x7FFFu + ((u >> 16) & 1u);
  return (short)(u >> 16);
}
__device__ __forceinline__ unsigned pkh(float a, float b) {  // 2xf32 -> packed f16 (RTN)
  _Float16 h0 = (_Float16)a, h1 = (_Float16)b;
  return (unsigned)__builtin_bit_cast(unsigned short, h0)
       | ((unsigned)__builtin_bit_cast(unsigned short, h1) << 16);
}

__global__ __launch_bounds__(256, 4) void relpos_sdpa_r3(
    const float* __restrict__ Q, const float* __restrict__ K,
    const float* __restrict__ V, const float* __restrict__ Ub,
    const float* __restrict__ Vb, const float* __restrict__ R,
    float* __restrict__ O)
{
  const int n    = blockIdx.x;            // same-n blocks land on one XCD (id%8)
  const int h    = n & (NHD - 1);
  const int a0   = blockIdx.y * 64;
  const int tid  = threadIdx.x;
  const int lane = tid & 63, wave = tid >> 6;
  const int l15  = lane & 15, quad = lane >> 4;

  const float* Qn = Q + (size_t)n * SQ * HD;
  const float* Kn = K + (size_t)n * SQ * HD;
  const float* Vn = V + (size_t)n * SQ * HD;
  const float* Rh = R + (size_t)h * RMAX * HD;

  // LDS: Kb f16 [key][72] (9216 B, aliased by Ps bf16 [q][68] after syncC),
  //      Vt bf16 [d:80][72] (11520 B, row 64 = ones, rows 65-79 don't-care),
  //      Pb f16 [slot:128][70] (17920 B). Total 38656 -> 4 blocks/CU.
  __shared__ __align__(16) char lds[38656];
  _Float16* Kb = (_Float16*)lds;
  short*    Ps = (short*)lds;
  short*    Vt = (short*)(lds + 9216);
  _Float16* Pb = (_Float16*)(lds + 9216 + 11520);

  // ---- persistent q fragments (A-layout: m=l15, k=quad*8+j, frag per 32-k) ----
  f16x8 quF[2], qvF[5][2];
#pragma unroll
  for (int ks = 0; ks < 2; ++ks) {
    const int db = ks * 32 + quad * 8;
    float ub[8], vb[8];
#pragma unroll
    for (int j = 0; j < 8; ++j) { ub[j] = Ub[h*HD + db + j]; vb[j] = Vb[h*HD + db + j]; }
    {
      const float* p = Qn + (size_t)(a0 + 16*wave + l15) * HD + db;
      f16x8 f;
#pragma unroll
      for (int j = 0; j < 8; ++j) f[j] = (_Float16)(p[j] * 0.125f + ub[j]);
      quF[ks] = f;
    }
#pragma unroll
    for (int rt = 0; rt < 5; ++rt) {
      int row = a0 + 16*rt + l15; if (row > SQ-1) row = SQ-1;  // clamp rows unused
      const float* p = Qn + (size_t)row * HD + db;
      f16x8 f;
#pragma unroll
      for (int j = 0; j < 8; ++j) f[j] = (_Float16)(p[j] * 0.125f + vb[j]);
      qvF[rt][ks] = f;
    }
  }

  if (tid < 64) Vt[64*72 + tid] = (short)0x3F80;   // ones row (l-accumulator)

  f32x4 Oacc[5];
#pragma unroll
  for (int ct = 0; ct < 5; ++ct) Oacc[ct] = (f32x4){0.f, 0.f, 0.f, 0.f};

  // band: wave w computes ring cols c = jstart+16w+l15 (B from global R),
  // rows 0..65 stored (row 64 used by ii=63,u=1 gathers; 65 = pad).
  auto band = [&](int jstart) {
    const int c    = jstart + 16*wave + l15;
    const int j    = (c + 2048) & (SQ - 1);
    const int slot = (c + 2048) & 127;
    const float* rp = Rh + (size_t)j * HD + quad * 8;
    f16x8 B0, B1;
    {
      float4 x0 = *(const float4*)(rp),      x1 = *(const float4*)(rp + 4);
      float4 y0 = *(const float4*)(rp + 32), y1 = *(const float4*)(rp + 36);
#pragma unroll
      for (int t = 0; t < 4; ++t) { B0[t] = (_Float16)(&x0.x)[t]; B0[t+4] = (_Float16)(&x1.x)[t]; }
#pragma unroll
      for (int t = 0; t < 4; ++t) { B1[t] = (_Float16)(&y0.x)[t]; B1[t+4] = (_Float16)(&y1.x)[t]; }
    }
#pragma unroll
    for (int rt = 0; rt < 5; ++rt) {
      f32x4 acc = (f32x4){0.f, 0.f, 0.f, 0.f};
      acc = MFMA_F16(qvF[rt][0], B0, acc);
      acc = MFMA_F16(qvF[rt][1], B1, acc);
      const int row = 16*rt + 4*quad;
      if (rt < 4) {
        *(unsigned*)&Pb[slot*70 + row]     = pkh(acc[0], acc[1]);
        *(unsigned*)&Pb[slot*70 + row + 2] = pkh(acc[2], acc[3]);
      } else if (quad == 0) {
        *(unsigned*)&Pb[slot*70 + row]     = pkh(acc[0], acc[1]);  // rows 64,65
      }
    }
  };

  band(-a0 - 65);   // prologue: fills all 128 ring slots for iter 0
  band(-a0 - 1);

  const int sr = tid >> 2, sc4 = tid & 3;
  const int iiB = 16*wave + 4*quad;

  for (int k0 = 0; k0 < SQ; k0 += 64) {
    __syncthreads();   // A: prev-iter Pb/Ps/Vt/Kb reads done

    { // stage K tile (f16)
      const float* src = Kn + (size_t)(k0 + sr) * HD + sc4 * 16;
      float4 x0 = *(const float4*)(src),     x1 = *(const float4*)(src + 4);
      float4 y0 = *(const float4*)(src + 8), y1 = *(const float4*)(src + 12);
      f16x8 lo, hi;
#pragma unroll
      for (int t = 0; t < 4; ++t) { lo[t] = (_Float16)(&x0.x)[t]; lo[t+4] = (_Float16)(&x1.x)[t]; }
#pragma unroll
      for (int t = 0; t < 4; ++t) { hi[t] = (_Float16)(&y0.x)[t]; hi[t+4] = (_Float16)(&y1.x)[t]; }
      *(f16x8*)&Kb[sr*72 + sc4*16]     = lo;
      *(f16x8*)&Kb[sr*72 + sc4*16 + 8] = hi;
    }
    { // stage V transposed (bf16), pair-packed b32, xor-swizzled
      const int g = lane >> 3;
#pragma unroll
      for (int i = 0; i < 8; ++i) {
        int bp = 8*wave + (i ^ g);
        float v0 = Vn[(size_t)(k0 + 2*bp)     * HD + lane];
        float v1 = Vn[(size_t)(k0 + 2*bp + 1) * HD + lane];
        unsigned pk = (unsigned)(unsigned short)f2b(v0)
                    | ((unsigned)(unsigned short)f2b(v1) << 16);
        *(unsigned*)&Vt[lane*72 + 2*bp] = pk;
      }
    }
    __syncthreads();   // B: Kb/Vt staged, prev band's Pb writes visible

    // ---- content scores ----
    f32x4 sc[4];
#pragma unroll
    for (int ct = 0; ct < 4; ++ct) {
      f16x8 b0 = *(const f16x8*)&Kb[(16*ct + l15)*72 + quad*8];
      f16x8 b1 = *(const f16x8*)&Kb[(16*ct + l15)*72 + 32 + quad*8];
      f32x4 acc = (f32x4){0.f, 0.f, 0.f, 0.f};
      acc = MFMA_F16(quF[0], b0, acc);
      acc = MFMA_F16(quF[1], b1, acc);
      sc[ct] = acc;
    }

    // ---- gather + fixed-shift exp (in place; writes deferred past syncC) ----
    const int dlt = k0 - a0;
#pragma unroll
    for (int r = 0; r < 4; ++r) {
      const int ii = iiB + r;
#pragma unroll
      for (int ct = 0; ct < 4; ++ct) {
        const int e    = dlt + 16*ct + l15 - ii;
        const int u    = (e > 0) ? 1 : 0;
        const int slot = (e - 1 - u + 2048) & 127;
        float pos = (float)Pb[slot*70 + ii + u];
        float s   = sc[ct][r] + ((e == 1) ? 0.f : pos);
        sc[ct][r] = __expf(s - 40.0f);    // bounded: |s| <~ 74 -> safe in fp32/bf16
      }
    }
    __syncthreads();   // C: all waves' Kb reads + Pb gathers done

    // Ps (aliases Kb) — wave-private rows, no barrier before own reads
#pragma unroll
    for (int r = 0; r < 4; ++r)
#pragma unroll
      for (int ct = 0; ct < 4; ++ct)
        Ps[(iiB + r)*68 + 16*ct + l15] = f2b(sc[ct][r]);

    b16x8 pA0 = *(const b16x8*)&Ps[(16*wave + l15)*68 + quad*8];
    b16x8 pA1 = *(const b16x8*)&Ps[(16*wave + l15)*68 + 32 + quad*8];
#pragma unroll
    for (int ct = 0; ct < 5; ++ct) {       // ct=4: ones column -> l = sum(p)
      b16x8 v0 = *(const b16x8*)&Vt[(16*ct + l15)*72 + quad*8];
      b16x8 v1 = *(const b16x8*)&Vt[(16*ct + l15)*72 + 32 + quad*8];
      Oacc[ct] = MFMA_BF16(pA0, v0, Oacc[ct]);
      Oacc[ct] = MFMA_BF16(pA1, v1, Oacc[ct]);
    }

    if (k0 < SQ - 64) band(k0 + 64 - a0 - 1);   // next iter's 64 new ring cols
  }

  // ---- epilogue: O = Oacc / l,  l broadcast from lane l15==0 of own quad ----
#pragma unroll
  for (int r = 0; r < 4; ++r) {
    float lv  = Oacc[4][r];
    float l   = __shfl(lv, lane & 48);
    float inv = 1.0f / l;
    const size_t rowo = (size_t)n * SQ * HD + (size_t)(a0 + iiB + r) * HD;
#pragma unroll
    for (int ct = 0; ct < 4; ++ct)
      O[rowo + 16*ct + l15] = Oacc[ct][r] * inv;
  }
}

extern "C" void kernel_launch(void* const* d_in, const int* in_sizes, int n_in,
                              void* d_out, int out_size, void* d_ws, size_t ws_size,
                              hipStream_t stream) {
  const float* Q  = (const float*)d_in[0];
  const float* K  = (const float*)d_in[1];
  const float* V  = (const float*)d_in[2];
  const float* Ub = (const float*)d_in[3];  // (1,16,1,64)
  const float* Vb = (const float*)d_in[4];
  const float* R  = (const float*)d_in[5];  // (16,2048,64)
  float* O = (float*)d_out;

  dim3 grid(64, 16);   // x = n (XCD locality), y = q-tile
  relpos_sdpa_r3<<<grid, 256, 0, stream>>>(Q, K, V, Ub, Vb, R, O);
}

// Round 6
// 193.737 us; speedup vs baseline: 1.1630x; 1.1630x over previous
//
#include <hip/hip_runtime.h>

// RelativePositionSDPA — R5: R3's known-passing kernel structure VERBATIM
// (3 barriers/iter, LDS-staged K/V, Pb ring + Ps-aliasing-Kb, RTN Ps, band at
// loop end), fed by precomputed operands in d_ws: Kh f16 [n][s][d], Vt bf16
// [n][80][s] (transposed, ones-row 64), R16 f16 [h][1024][d]. All staging is
// pure b128 copies — zero conversion math in the hot loop. Bisection vs R4:
// if this fails, the precompute pass is the bug; if it passes, R4's 2-barrier
// restructure was.
//
// Shift algebra (verified R0 fp32, R2/R3 passing): e = b-a, u = (e>0),
// ring col c = e-1-u, slot = c&127, pos = Pb[slot][ii+u], zero at e==1.
// Fixed-shift softmax p = exp(s-40); l = sum(p) via ones-row of V^T (ct=4).

#define SQ    1024
#define HD    64
#define NHD   16
#define RMAX  2048

typedef _Float16 f16x8 __attribute__((ext_vector_type(8)));
typedef _Float16 f16x4 __attribute__((ext_vector_type(4)));
typedef short    b16x8 __attribute__((ext_vector_type(8)));
typedef float    f32x4 __attribute__((ext_vector_type(4)));

#define MFMA_F16(A,B,C)  __builtin_amdgcn_mfma_f32_16x16x32_f16((A),(B),(C),0,0,0)
#define MFMA_BF16(A,B,C) __builtin_amdgcn_mfma_f32_16x16x32_bf16((A),(B),(C),0,0,0)

// ws layout
#define KH_OFF   0                       // f16 [64][1024][64]   8 MB
#define VT_OFF   (8u << 20)              // bf16 [64][80][1024]  10 MB
#define R16_OFF  (18u << 20)             // f16 [16][1024][64]   2 MB
#define WS_NEED  (20u << 20)

__device__ __forceinline__ short f2b(float f) {          // fp32 -> bf16 RTN-even
  unsigned u = __builtin_bit_cast(unsigned, f);
  u += 0x7FFFu + ((u >> 16) & 1u);
  return (short)(u >> 16);
}
__device__ __forceinline__ unsigned pkh(float a, float b) {  // 2xf32 -> packed f16 RTN
  _Float16 h0 = (_Float16)a, h1 = (_Float16)b;
  return (unsigned)__builtin_bit_cast(unsigned short, h0)
       | ((unsigned)__builtin_bit_cast(unsigned short, h1) << 16);
}

// ---------------- precompute kernels ----------------

__global__ __launch_bounds__(256) void precvt_kr(
    const float* __restrict__ K, const float* __restrict__ R,
    _Float16* __restrict__ Kh, _Float16* __restrict__ R16)
{
  const int idx = blockIdx.x * 256 + threadIdx.x;        // float4 index
  const int nk4 = (64 * SQ * HD) / 4;                    // 1048576
  if (idx < nk4) {
    float4 v = ((const float4*)K)[idx];
    f16x4 o = { (_Float16)v.x, (_Float16)v.y, (_Float16)v.z, (_Float16)v.w };
    *(f16x4*)(Kh + 4 * (size_t)idx) = o;
  } else {
    int rr = idx - nk4;                                  // < 16*16384 = 262144
    int h  = rr >> 14, off = rr & 16383;                 // 16384 float4/head (1024 rows)
    float4 v = ((const float4*)R)[((size_t)h << 15) + off];   // src head stride 2048 rows
    f16x4 o = { (_Float16)v.x, (_Float16)v.y, (_Float16)v.z, (_Float16)v.w };
    *(f16x4*)(R16 + 4 * (((size_t)h << 14) + off)) = o;
  }
}

__global__ __launch_bounds__(256) void prevt_v(
    const float* __restrict__ V, short* __restrict__ Vt)
{
  __shared__ float t[64][65];
  const int n = blockIdx.x, st = blockIdx.y, tid = threadIdx.x;
  {
    const int row = tid >> 2, c0 = (tid & 3) * 16;
    const float* src = V + ((size_t)n * SQ + st * 64 + row) * HD + c0;
#pragma unroll
    for (int i = 0; i < 4; ++i) {
      float4 x = ((const float4*)src)[i];
      t[row][c0 + 4*i + 0] = x.x; t[row][c0 + 4*i + 1] = x.y;
      t[row][c0 + 4*i + 2] = x.z; t[row][c0 + 4*i + 3] = x.w;
    }
  }
  __syncthreads();
  {
    const int d = tid >> 2, s0 = (tid & 3) * 16;
    short* dst = Vt + ((size_t)n * 80 + d) * SQ + st * 64 + s0;
#pragma unroll
    for (int i = 0; i < 8; ++i) {
      unsigned pk = (unsigned)(unsigned short)f2b(t[s0 + 2*i][d])
                  | ((unsigned)(unsigned short)f2b(t[s0 + 2*i + 1][d]) << 16);
      *(unsigned*)(dst + 2*i) = pk;
    }
  }
  if (tid < 64) {          // ones row (l accumulator) + zero pad rows
    const int s = st * 64 + tid;
    Vt[((size_t)n * 80 + 64) * SQ + s] = (short)0x3F80;
#pragma unroll
    for (int r = 65; r < 80; ++r) Vt[((size_t)n * 80 + r) * SQ + s] = 0;
  }
}

// ---------------- main flash kernel (R5 = R3 structure + precomputed feeds) --

__global__ __launch_bounds__(256, 4) void relpos_sdpa_r5(
    const float* __restrict__ Q, const _Float16* __restrict__ Kh,
    const short* __restrict__ Vtg, const _Float16* __restrict__ R16,
    const float* __restrict__ Ub, const float* __restrict__ Vb,
    float* __restrict__ O)
{
  const int n    = blockIdx.x;
  const int h    = n & (NHD - 1);
  const int a0   = blockIdx.y * 64;
  const int tid  = threadIdx.x;
  const int lane = tid & 63, wave = tid >> 6;
  const int l15  = lane & 15, quad = lane >> 4;

  const float*    Qn  = Q   + (size_t)n * SQ * HD;
  const _Float16* Khn = Kh  + (size_t)n * SQ * HD;
  const short*    Vgn = Vtg + (size_t)n * 80 * SQ;
  const _Float16* Rh  = R16 + (size_t)h * SQ * HD;

  // LDS layout identical to R3: Kb f16 [64][72] (aliased by Ps bf16 [64][68]
  // after syncC), Vt bf16 [80][72], Pb f16 [128][70]. Total 38656 B.
  __shared__ __align__(16) char lds[38656];
  _Float16* Kb = (_Float16*)lds;
  short*    Ps = (short*)lds;
  short*    Vt = (short*)(lds + 9216);
  _Float16* Pb = (_Float16*)(lds + 9216 + 11520);

  // ---- persistent q fragments (A-layout: m=l15, k=quad*8+j, frag per 32-k) ----
  f16x8 quF[2], qvF[5][2];
#pragma unroll
  for (int ks = 0; ks < 2; ++ks) {
    const int db = ks * 32 + quad * 8;
    float ub[8], vb[8];
#pragma unroll
    for (int j = 0; j < 8; ++j) { ub[j] = Ub[h*HD + db + j]; vb[j] = Vb[h*HD + db + j]; }
    {
      const float* p = Qn + (size_t)(a0 + 16*wave + l15) * HD + db;
      f16x8 f;
#pragma unroll
      for (int j = 0; j < 8; ++j) f[j] = (_Float16)(p[j] * 0.125f + ub[j]);
      quF[ks] = f;
    }
#pragma unroll
    for (int rt = 0; rt < 5; ++rt) {
      int row = a0 + 16*rt + l15; if (row > SQ-1) row = SQ-1;  // clamp rows unused
      const float* p = Qn + (size_t)row * HD + db;
      f16x8 f;
#pragma unroll
      for (int j = 0; j < 8; ++j) f[j] = (_Float16)(p[j] * 0.125f + vb[j]);
      qvF[rt][ks] = f;
    }
  }

  if (tid < 64) Vt[64*72 + tid] = (short)0x3F80;   // ones row (l accumulator)

  f32x4 Oacc[5];
#pragma unroll
  for (int ct = 0; ct < 5; ++ct) Oacc[ct] = (f32x4){0.f, 0.f, 0.f, 0.f};

  // band: B-frags direct from precomputed f16 R16 (no conversion)
  auto band = [&](int jstart) {
    const int c    = jstart + 16*wave + l15;
    const int j    = (c + 2048) & (SQ - 1);
    const int slot = (c + 2048) & 127;
    const _Float16* rp = Rh + (size_t)j * HD + quad * 8;
    f16x8 B0 = *(const f16x8*)rp;
    f16x8 B1 = *(const f16x8*)(rp + 32);
#pragma unroll
    for (int rt = 0; rt < 5; ++rt) {
      f32x4 acc = (f32x4){0.f, 0.f, 0.f, 0.f};
      acc = MFMA_F16(qvF[rt][0], B0, acc);
      acc = MFMA_F16(qvF[rt][1], B1, acc);
      const int row = 16*rt + 4*quad;
      if (rt < 4) {
        *(unsigned*)&Pb[slot*70 + row]     = pkh(acc[0], acc[1]);
        *(unsigned*)&Pb[slot*70 + row + 2] = pkh(acc[2], acc[3]);
      } else if (quad == 0) {
        *(unsigned*)&Pb[slot*70 + row]     = pkh(acc[0], acc[1]);  // rows 64,65
      }
    }
  };

  band(-a0 - 65);   // prologue: fill all 128 ring slots for iter 0
  band(-a0 - 1);

  const int sr = tid >> 2, sc4 = tid & 3;
  const int iiB = 16*wave + 4*quad;

  for (int k0 = 0; k0 < SQ; k0 += 64) {
    __syncthreads();   // A: prev-iter Pb/Ps/Vt/Kb reads done

    { // stage K tile: pure b128 copy of precomputed f16
      const _Float16* src = Khn + (size_t)(k0 + sr) * HD + sc4 * 16;
      *(f16x8*)&Kb[sr*72 + sc4*16]     = *(const f16x8*)src;
      *(f16x8*)&Kb[sr*72 + sc4*16 + 8] = *(const f16x8*)(src + 8);
    }
    { // stage V^T tile: pure b128 copy of precomputed bf16 [d][key]
      const short* src = Vgn + (size_t)sr * SQ + k0 + sc4 * 16;
      *(b16x8*)&Vt[sr*72 + sc4*16]     = *(const b16x8*)src;
      *(b16x8*)&Vt[sr*72 + sc4*16 + 8] = *(const b16x8*)(src + 8);
    }
    __syncthreads();   // B: Kb/Vt staged, prologue/prev band's Pb writes visible

    // ---- content scores ----
    f32x4 sc[4];
#pragma unroll
    for (int ct = 0; ct < 4; ++ct) {
      f16x8 b0 = *(const f16x8*)&Kb[(16*ct + l15)*72 + quad*8];
      f16x8 b1 = *(const f16x8*)&Kb[(16*ct + l15)*72 + 32 + quad*8];
      f32x4 acc = (f32x4){0.f, 0.f, 0.f, 0.f};
      acc = MFMA_F16(quF[0], b0, acc);
      acc = MFMA_F16(quF[1], b1, acc);
      sc[ct] = acc;
    }

    // ---- gather + fixed-shift exp ----
    const int dlt = k0 - a0;
#pragma unroll
    for (int r = 0; r < 4; ++r) {
      const int ii = iiB + r;
#pragma unroll
      for (int ct = 0; ct < 4; ++ct) {
        const int e    = dlt + 16*ct + l15 - ii;
        const int u    = (e > 0) ? 1 : 0;
        const int slot = (e - 1 - u + 2048) & 127;
        float pos = (float)Pb[slot*70 + ii + u];
        float s   = sc[ct][r] + ((e == 1) ? 0.f : pos);
        sc[ct][r] = __expf(s - 40.0f);   // bounded: |s| <~ 74 -> safe
      }
    }
    __syncthreads();   // C: all waves' Kb reads + Pb gathers done

    // Ps (aliases Kb) — wave-private rows, RTN as in R3
#pragma unroll
    for (int r = 0; r < 4; ++r)
#pragma unroll
      for (int ct = 0; ct < 4; ++ct)
        Ps[(iiB + r)*68 + 16*ct + l15] = f2b(sc[ct][r]);

    b16x8 pA0 = *(const b16x8*)&Ps[(16*wave + l15)*68 + quad*8];
    b16x8 pA1 = *(const b16x8*)&Ps[(16*wave + l15)*68 + 32 + quad*8];
#pragma unroll
    for (int ct = 0; ct < 5; ++ct) {       // ct=4: ones row -> l = sum(p)
      b16x8 v0 = *(const b16x8*)&Vt[(16*ct + l15)*72 + quad*8];
      b16x8 v1 = *(const b16x8*)&Vt[(16*ct + l15)*72 + 32 + quad*8];
      Oacc[ct] = MFMA_BF16(pA0, v0, Oacc[ct]);
      Oacc[ct] = MFMA_BF16(pA1, v1, Oacc[ct]);
    }

    if (k0 < SQ - 64) band(k0 + 64 - a0 - 1);   // next iter's 64 new ring cols
  }

  // ---- epilogue: O = Oacc / l, l broadcast from l15==0 lane of own quad ----
#pragma unroll
  for (int r = 0; r < 4; ++r) {
    float l   = __shfl(Oacc[4][r], lane & 48);
    float inv = 1.0f / l;
    const size_t rowo = (size_t)n * SQ * HD + (size_t)(a0 + iiB + r) * HD;
#pragma unroll
    for (int ct = 0; ct < 4; ++ct)
      O[rowo + 16*ct + l15] = Oacc[ct][r] * inv;
  }
}

// ---------------- fallback (original R3, raw inputs) for small ws ----------------

__global__ __launch_bounds__(256, 4) void relpos_sdpa_r3(
    const float* __restrict__ Q, const float* __restrict__ K,
    const float* __restrict__ V, const float* __restrict__ Ub,
    const float* __restrict__ Vb, const float* __restrict__ R,
    float* __restrict__ O)
{
  const int n    = blockIdx.x;
  const int h    = n & (NHD - 1);
  const int a0   = blockIdx.y * 64;
  const int tid  = threadIdx.x;
  const int lane = tid & 63, wave = tid >> 6;
  const int l15  = lane & 15, quad = lane >> 4;

  const float* Qn = Q + (size_t)n * SQ * HD;
  const float* Kn = K + (size_t)n * SQ * HD;
  const float* Vn = V + (size_t)n * SQ * HD;
  const float* Rh = R + (size_t)h * RMAX * HD;

  __shared__ __align__(16) char lds[38656];
  _Float16* Kb = (_Float16*)lds;
  short*    Ps = (short*)lds;
  short*    Vt = (short*)(lds + 9216);
  _Float16* Pb = (_Float16*)(lds + 9216 + 11520);

  f16x8 quF[2], qvF[5][2];
#pragma unroll
  for (int ks = 0; ks < 2; ++ks) {
    const int db = ks * 32 + quad * 8;
    float ub[8], vb[8];
#pragma unroll
    for (int j = 0; j < 8; ++j) { ub[j] = Ub[h*HD + db + j]; vb[j] = Vb[h*HD + db + j]; }
    {
      const float* p = Qn + (size_t)(a0 + 16*wave + l15) * HD + db;
      f16x8 f;
#pragma unroll
      for (int j = 0; j < 8; ++j) f[j] = (_Float16)(p[j] * 0.125f + ub[j]);
      quF[ks] = f;
    }
#pragma unroll
    for (int rt = 0; rt < 5; ++rt) {
      int row = a0 + 16*rt + l15; if (row > SQ-1) row = SQ-1;
      const float* p = Qn + (size_t)row * HD + db;
      f16x8 f;
#pragma unroll
      for (int j = 0; j < 8; ++j) f[j] = (_Float16)(p[j] * 0.125f + vb[j]);
      qvF[rt][ks] = f;
    }
  }

  if (tid < 64) Vt[64*72 + tid] = (short)0x3F80;

  f32x4 Oacc[5];
#pragma unroll
  for (int ct = 0; ct < 5; ++ct) Oacc[ct] = (f32x4){0.f, 0.f, 0.f, 0.f};

  auto band = [&](int jstart) {
    const int c    = jstart + 16*wave + l15;
    const int j    = (c + 2048) & (SQ - 1);
    const int slot = (c + 2048) & 127;
    const float* rp = Rh + (size_t)j * HD + quad * 8;
    f16x8 B0, B1;
    {
      float4 x0 = *(const float4*)(rp),      x1 = *(const float4*)(rp + 4);
      float4 y0 = *(const float4*)(rp + 32), y1 = *(const float4*)(rp + 36);
#pragma unroll
      for (int t = 0; t < 4; ++t) { B0[t] = (_Float16)(&x0.x)[t]; B0[t+4] = (_Float16)(&x1.x)[t]; }
#pragma unroll
      for (int t = 0; t < 4; ++t) { B1[t] = (_Float16)(&y0.x)[t]; B1[t+4] = (_Float16)(&y1.x)[t]; }
    }
#pragma unroll
    for (int rt = 0; rt < 5; ++rt) {
      f32x4 acc = (f32x4){0.f, 0.f, 0.f, 0.f};
      acc = MFMA_F16(qvF[rt][0], B0, acc);
      acc = MFMA_F16(qvF[rt][1], B1, acc);
      const int row = 16*rt + 4*quad;
      if (rt < 4) {
        *(unsigned*)&Pb[slot*70 + row]     = pkh(acc[0], acc[1]);
        *(unsigned*)&Pb[slot*70 + row + 2] = pkh(acc[2], acc[3]);
      } else if (quad == 0) {
        *(unsigned*)&Pb[slot*70 + row]     = pkh(acc[0], acc[1]);
      }
    }
  };

  band(-a0 - 65);
  band(-a0 - 1);

  const int sr = tid >> 2, sc4 = tid & 3;
  const int iiB = 16*wave + 4*quad;

  for (int k0 = 0; k0 < SQ; k0 += 64) {
    __syncthreads();
    {
      const float* src = Kn + (size_t)(k0 + sr) * HD + sc4 * 16;
      float4 x0 = *(const float4*)(src),     x1 = *(const float4*)(src + 4);
      float4 y0 = *(const float4*)(src + 8), y1 = *(const float4*)(src + 12);
      f16x8 lo, hi;
#pragma unroll
      for (int t = 0; t < 4; ++t) { lo[t] = (_Float16)(&x0.x)[t]; lo[t+4] = (_Float16)(&x1.x)[t]; }
#pragma unroll
      for (int t = 0; t < 4; ++t) { hi[t] = (_Float16)(&y0.x)[t]; hi[t+4] = (_Float16)(&y1.x)[t]; }
      *(f16x8*)&Kb[sr*72 + sc4*16]     = lo;
      *(f16x8*)&Kb[sr*72 + sc4*16 + 8] = hi;
    }
    {
      const int g = lane >> 3;
#pragma unroll
      for (int i = 0; i < 8; ++i) {
        int bp = 8*wave + (i ^ g);
        float v0 = Vn[(size_t)(k0 + 2*bp)     * HD + lane];
        float v1 = Vn[(size_t)(k0 + 2*bp + 1) * HD + lane];
        unsigned pk = (unsigned)(unsigned short)f2b(v0)
                    | ((unsigned)(unsigned short)f2b(v1) << 16);
        *(unsigned*)&Vt[lane*72 + 2*bp] = pk;
      }
    }
    __syncthreads();

    f32x4 sc[4];
#pragma unroll
    for (int ct = 0; ct < 4; ++ct) {
      f16x8 b0 = *(const f16x8*)&Kb[(16*ct + l15)*72 + quad*8];
      f16x8 b1 = *(const f16x8*)&Kb[(16*ct + l15)*72 + 32 + quad*8];
      f32x4 acc = (f32x4){0.f, 0.f, 0.f, 0.f};
      acc = MFMA_F16(quF[0], b0, acc);
      acc = MFMA_F16(quF[1], b1, acc);
      sc[ct] = acc;
    }

    const int dlt = k0 - a0;
#pragma unroll
    for (int r = 0; r < 4; ++r) {
      const int ii = iiB + r;
#pragma unroll
      for (int ct = 0; ct < 4; ++ct) {
        const int e    = dlt + 16*ct + l15 - ii;
        const int u    = (e > 0) ? 1 : 0;
        const int slot = (e - 1 - u + 2048) & 127;
        float pos = (float)Pb[slot*70 + ii + u];
        float s   = sc[ct][r] + ((e == 1) ? 0.f : pos);
        sc[ct][r] = __expf(s - 40.0f);
      }
    }
    __syncthreads();

#pragma unroll
    for (int r = 0; r < 4; ++r)
#pragma unroll
      for (int ct = 0; ct < 4; ++ct)
        Ps[(iiB + r)*68 + 16*ct + l15] = f2b(sc[ct][r]);

    b16x8 pA0 = *(const b16x8*)&Ps[(16*wave + l15)*68 + quad*8];
    b16x8 pA1 = *(const b16x8*)&Ps[(16*wave + l15)*68 + 32 + quad*8];
#pragma unroll
    for (int ct = 0; ct < 5; ++ct) {
      b16x8 v0 = *(const b16x8*)&Vt[(16*ct + l15)*72 + quad*8];
      b16x8 v1 = *(const b16x8*)&Vt[(16*ct + l15)*72 + 32 + quad*8];
      Oacc[ct] = MFMA_BF16(pA0, v0, Oacc[ct]);
      Oacc[ct] = MFMA_BF16(pA1, v1, Oacc[ct]);
    }

    if (k0 < SQ - 64) band(k0 + 64 - a0 - 1);
  }

#pragma unroll
  for (int r = 0; r < 4; ++r) {
    float l   = __shfl(Oacc[4][r], lane & 48);
    float inv = 1.0f / l;
    const size_t rowo = (size_t)n * SQ * HD + (size_t)(a0 + iiB + r) * HD;
#pragma unroll
    for (int ct = 0; ct < 4; ++ct)
      O[rowo + 16*ct + l15] = Oacc[ct][r] * inv;
  }
}

extern "C" void kernel_launch(void* const* d_in, const int* in_sizes, int n_in,
                              void* d_out, int out_size, void* d_ws, size_t ws_size,
                              hipStream_t stream) {
  const float* Q  = (const float*)d_in[0];
  const float* K  = (const float*)d_in[1];
  const float* V  = (const float*)d_in[2];
  const float* Ub = (const float*)d_in[3];  // (1,16,1,64)
  const float* Vb = (const float*)d_in[4];
  const float* R  = (const float*)d_in[5];  // (16,2048,64)
  float* O = (float*)d_out;

  if (ws_size >= WS_NEED) {
    _Float16* Kh  = (_Float16*)((char*)d_ws + KH_OFF);
    short*    Vt  = (short*)((char*)d_ws + VT_OFF);
    _Float16* R16 = (_Float16*)((char*)d_ws + R16_OFF);

    precvt_kr<<<5120, 256, 0, stream>>>(K, R, Kh, R16);
    prevt_v<<<dim3(64, 16), 256, 0, stream>>>(V, Vt);

    dim3 grid(64, 16);   // x = n (XCD locality), y = q-tile
    relpos_sdpa_r5<<<grid, 256, 0, stream>>>(Q, Kh, Vt, R16, Ub, Vb, O);
  } else {
    dim3 grid(64, 16);
    relpos_sdpa_r3<<<grid, 256, 0, stream>>>(Q, K, V, Ub, Vb, R, O);
  }
}

// Round 8
// 188.831 us; speedup vs baseline: 1.1932x; 1.0260x over previous
//
#include <hip/hip_runtime.h>

// RelativePositionSDPA — R7 = R6 with the compile fix (pkb via own f2b instead
// of __builtin_bit_cast on __hip_bfloat162, which is not trivially copyable).
//
// R6 design: R5 structure (3 barriers, LDS-staged K/V from precomputed ws
// operands — proven) + conflict-free row-pair-packed Pb ring (u32[33][132];
// gathers & writes uniform 2 lanes/bank = free) + merged single precompute.
//
// Shift algebra (verified R0 fp32, R2/R3/R5 passing): e = b-a, u = (e>0),
// ring col c = e-1-u, slot = c&127, row i = ii+u, pos = ring[i][slot],
// zero at e==1. Fixed-shift softmax p = exp(s-40); l = sum(p) via ones-row
// 64 of V^T accumulated in the PV MFMA (ct=4).

#define SQ    1024
#define HD    64
#define NHD   16
#define RMAX  2048

typedef _Float16 f16x8 __attribute__((ext_vector_type(8)));
typedef _Float16 f16x4 __attribute__((ext_vector_type(4)));
typedef short    b16x8 __attribute__((ext_vector_type(8)));
typedef float    f32x4 __attribute__((ext_vector_type(4)));

#define MFMA_F16(A,B,C)  __builtin_amdgcn_mfma_f32_16x16x32_f16((A),(B),(C),0,0,0)
#define MFMA_BF16(A,B,C) __builtin_amdgcn_mfma_f32_16x16x32_bf16((A),(B),(C),0,0,0)

// ws layout
#define KH_OFF   0                       // f16 [64][1024][64]   8 MB
#define VT_OFF   (8u << 20)              // bf16 [64][80][1024]  10 MB
#define R16_OFF  (18u << 20)             // f16 [16][1024][64]   2 MB
#define WS_NEED  (20u << 20)

__device__ __forceinline__ short f2b(float f) {          // fp32 -> bf16 RTN-even
  unsigned u = __builtin_bit_cast(unsigned, f);
  u += 0x7FFFu + ((u >> 16) & 1u);
  return (short)(u >> 16);
}
__device__ __forceinline__ unsigned pkh(float a, float b) {  // 2xf32 -> packed f16 RTN
  _Float16 h0 = (_Float16)a, h1 = (_Float16)b;
  return (unsigned)__builtin_bit_cast(unsigned short, h0)
       | ((unsigned)__builtin_bit_cast(unsigned short, h1) << 16);
}
__device__ __forceinline__ unsigned pkb(float a, float b) {  // 2xf32 -> packed bf16 RTN
  return (unsigned)(unsigned short)f2b(a)
       | ((unsigned)(unsigned short)f2b(b) << 16);
}

// ---------------- merged precompute kernel ----------------
// blocks [0,1024): V transpose+cvt (n = b>>4, seg = b&15)
// blocks [1024,6144): K and R fp32->f16 copies

__global__ __launch_bounds__(256) void preprep(
    const float* __restrict__ K, const float* __restrict__ R,
    const float* __restrict__ V,
    _Float16* __restrict__ Kh, _Float16* __restrict__ R16,
    short* __restrict__ Vt)
{
  __shared__ float t[64][65];
  const int bid = blockIdx.x, tid = threadIdx.x;
  if (bid < 1024) {
    const int n = bid >> 4, st = bid & 15;
    {
      const int row = tid >> 2, c0 = (tid & 3) * 16;
      const float* src = V + ((size_t)n * SQ + st * 64 + row) * HD + c0;
#pragma unroll
      for (int i = 0; i < 4; ++i) {
        float4 x = ((const float4*)src)[i];
        t[row][c0 + 4*i + 0] = x.x; t[row][c0 + 4*i + 1] = x.y;
        t[row][c0 + 4*i + 2] = x.z; t[row][c0 + 4*i + 3] = x.w;
      }
    }
    __syncthreads();
    {
      const int d = tid >> 2, s0 = (tid & 3) * 16;
      short* dst = Vt + ((size_t)n * 80 + d) * SQ + st * 64 + s0;
#pragma unroll
      for (int i = 0; i < 8; ++i)
        *(unsigned*)(dst + 2*i) = pkb(t[s0 + 2*i][d], t[s0 + 2*i + 1][d]);
    }
    if (tid < 64) {          // ones row (l accumulator) + zero pad rows
      const int s = st * 64 + tid;
      Vt[((size_t)n * 80 + 64) * SQ + s] = (short)0x3F80;
#pragma unroll
      for (int r = 65; r < 80; ++r) Vt[((size_t)n * 80 + r) * SQ + s] = 0;
    }
  } else {
    const int idx = (bid - 1024) * 256 + tid;            // float4 index
    const int nk4 = (64 * SQ * HD) / 4;                  // 1048576
    if (idx < nk4) {
      float4 v = ((const float4*)K)[idx];
      f16x4 o = { (_Float16)v.x, (_Float16)v.y, (_Float16)v.z, (_Float16)v.w };
      *(f16x4*)(Kh + 4 * (size_t)idx) = o;
    } else {
      int rr = idx - nk4;                                // < 262144
      int h  = rr >> 14, off = rr & 16383;               // 16384 float4/head
      float4 v = ((const float4*)R)[((size_t)h << 15) + off];  // src stride 2048 rows
      f16x4 o = { (_Float16)v.x, (_Float16)v.y, (_Float16)v.z, (_Float16)v.w };
      *(f16x4*)(R16 + 4 * (((size_t)h << 14) + off)) = o;
    }
  }
}

// ---------------- main flash kernel (R7) ----------------

__global__ __launch_bounds__(256, 4) void relpos_sdpa_r7(
    const float* __restrict__ Q, const _Float16* __restrict__ Kh,
    const short* __restrict__ Vtg, const _Float16* __restrict__ R16,
    const float* __restrict__ Ub, const float* __restrict__ Vb,
    float* __restrict__ O)
{
  const int n    = blockIdx.x;
  const int h    = n & (NHD - 1);
  const int a0   = blockIdx.y * 64;
  const int tid  = threadIdx.x;
  const int lane = tid & 63, wave = tid >> 6;
  const int l15  = lane & 15, quad = lane >> 4;

  const float*    Qn  = Q   + (size_t)n * SQ * HD;
  const _Float16* Khn = Kh  + (size_t)n * SQ * HD;
  const short*    Vgn = Vtg + (size_t)n * 80 * SQ;
  const _Float16* Rh  = R16 + (size_t)h * SQ * HD;

  // LDS: Kb f16 [64][72] 9216 B (Ps u16 [64][68] aliases after syncC),
  //      Vt bf16 [80][72] 11520 B, Pb2 ring u32 [33 row-pairs][132 slots]
  //      17424 B. Total 38160 B -> 4 blocks/CU.
  __shared__ __align__(16) char lds[38160];
  _Float16* Kb  = (_Float16*)lds;
  unsigned short* Ps = (unsigned short*)lds;
  short*    Vt  = (short*)(lds + 9216);
  unsigned* Pb2 = (unsigned*)(lds + 9216 + 11520);
  const _Float16* Pb2h = (const _Float16*)Pb2;

  // ---- persistent q fragments (A-layout: m=l15, k=quad*8+j, frag per 32-k) ----
  f16x8 quF[2], qvF[5][2];
#pragma unroll
  for (int ks = 0; ks < 2; ++ks) {
    const int db = ks * 32 + quad * 8;
    float ub[8], vb[8];
#pragma unroll
    for (int j = 0; j < 8; ++j) { ub[j] = Ub[h*HD + db + j]; vb[j] = Vb[h*HD + db + j]; }
    {
      const float* p = Qn + (size_t)(a0 + 16*wave + l15) * HD + db;
      f16x8 f;
#pragma unroll
      for (int j = 0; j < 8; ++j) f[j] = (_Float16)(p[j] * 0.125f + ub[j]);
      quF[ks] = f;
    }
#pragma unroll
    for (int rt = 0; rt < 5; ++rt) {
      int row = a0 + 16*rt + l15; if (row > SQ-1) row = SQ-1;  // clamp rows unused
      const float* p = Qn + (size_t)row * HD + db;
      f16x8 f;
#pragma unroll
      for (int j = 0; j < 8; ++j) f[j] = (_Float16)(p[j] * 0.125f + vb[j]);
      qvF[rt][ks] = f;
    }
  }

  if (tid < 64) Vt[64*72 + tid] = (short)0x3F80;   // ones row (l accumulator)

  f32x4 Oacc[5];
#pragma unroll
  for (int ct = 0; ct < 5; ++ct) Oacc[ct] = (f32x4){0.f, 0.f, 0.f, 0.f};

  // band: B-frags direct from precomputed f16 R16; writes row-pair-packed b32,
  // banks: word = rp*132+slot -> lanes consecutive, quads offset 8 -> 2/bank free.
  auto band = [&](int jstart) {
    const int c    = jstart + 16*wave + l15;
    const int j    = (c + 2048) & (SQ - 1);
    const int slot = (c + 2048) & 127;
    const _Float16* rp = Rh + (size_t)j * HD + quad * 8;
    f16x8 B0 = *(const f16x8*)rp;
    f16x8 B1 = *(const f16x8*)(rp + 32);
#pragma unroll
    for (int rt = 0; rt < 5; ++rt) {
      f32x4 acc = (f32x4){0.f, 0.f, 0.f, 0.f};
      acc = MFMA_F16(qvF[rt][0], B0, acc);
      acc = MFMA_F16(qvF[rt][1], B1, acc);
      if (rt < 4) {
        const int rp0 = 8*rt + 2*quad;                 // rows 16rt+4q .. +3
        Pb2[rp0*132 + slot]       = pkh(acc[0], acc[1]);
        Pb2[(rp0 + 1)*132 + slot] = pkh(acc[2], acc[3]);
      } else if (quad == 0) {
        Pb2[32*132 + slot] = pkh(acc[0], acc[1]);      // row 64 (+65 pad)
      }
    }
  };

  band(-a0 - 65);   // prologue: fill all 128 ring slots for iter 0
  band(-a0 - 1);

  const int sr = tid >> 2, sc4 = tid & 3;
  const int iiB = 16*wave + 4*quad;

  for (int k0 = 0; k0 < SQ; k0 += 64) {
    __syncthreads();   // A: prev-iter Pb2/Ps/Vt/Kb reads done

    { // stage K tile: pure b128 copy of precomputed f16
      const _Float16* src = Khn + (size_t)(k0 + sr) * HD + sc4 * 16;
      *(f16x8*)&Kb[sr*72 + sc4*16]     = *(const f16x8*)src;
      *(f16x8*)&Kb[sr*72 + sc4*16 + 8] = *(const f16x8*)(src + 8);
    }
    { // stage V^T tile: pure b128 copy of precomputed bf16 [d][key]
      const short* src = Vgn + (size_t)sr * SQ + k0 + sc4 * 16;
      *(b16x8*)&Vt[sr*72 + sc4*16]     = *(const b16x8*)src;
      *(b16x8*)&Vt[sr*72 + sc4*16 + 8] = *(const b16x8*)(src + 8);
    }
    __syncthreads();   // B: Kb/Vt staged, prev band's Pb2 writes visible

    // ---- content scores ----
    f32x4 sc[4];
#pragma unroll
    for (int ct = 0; ct < 4; ++ct) {
      f16x8 b0 = *(const f16x8*)&Kb[(16*ct + l15)*72 + quad*8];
      f16x8 b1 = *(const f16x8*)&Kb[(16*ct + l15)*72 + 32 + quad*8];
      f32x4 acc = (f32x4){0.f, 0.f, 0.f, 0.f};
      acc = MFMA_F16(quF[0], b0, acc);
      acc = MFMA_F16(quF[1], b1, acc);
      sc[ct] = acc;
    }

    // ---- gather (conflict-free) + fixed-shift exp ----
    const int dlt = k0 - a0;
#pragma unroll
    for (int r = 0; r < 4; ++r) {
      const int ii = iiB + r;
      const int adA = (ii >> 1) * 264 + (ii & 1);              // f16-elem base, u=0
      const int adB = ((ii + 1) >> 1) * 264 + ((ii + 1) & 1);  // u=1
#pragma unroll
      for (int ct = 0; ct < 4; ++ct) {
        const int e    = dlt + 16*ct + l15 - ii;
        const int u    = (e > 0) ? 1 : 0;
        const int slot = (e - 1 - u) & 127;
        float pos = (float)Pb2h[(u ? adB : adA) + 2*slot];
        float s   = sc[ct][r] + ((e == 1) ? 0.f : pos);
        sc[ct][r] = __expf(s - 40.0f);   // bounded: |s| <~ 74 -> safe
      }
    }
    __syncthreads();   // C: all waves' Kb reads + Pb2 gathers done

    // Ps (aliases Kb) — wave-private rows, packed bf16 RTN
#pragma unroll
    for (int r = 0; r < 4; ++r) {
      unsigned w0 = pkb(sc[0][r], sc[1][r]);
      unsigned w1 = pkb(sc[2][r], sc[3][r]);
      const int pbase = (iiB + r)*68 + l15;
      Ps[pbase]      = (unsigned short)w0;
      Ps[pbase + 16] = (unsigned short)(w0 >> 16);
      Ps[pbase + 32] = (unsigned short)w1;
      Ps[pbase + 48] = (unsigned short)(w1 >> 16);
    }

    b16x8 pA0 = *(const b16x8*)&Ps[(16*wave + l15)*68 + quad*8];
    b16x8 pA1 = *(const b16x8*)&Ps[(16*wave + l15)*68 + 32 + quad*8];
#pragma unroll
    for (int ct = 0; ct < 5; ++ct) {       // ct=4: ones row -> l = sum(p)
      b16x8 v0 = *(const b16x8*)&Vt[(16*ct + l15)*72 + quad*8];
      b16x8 v1 = *(const b16x8*)&Vt[(16*ct + l15)*72 + 32 + quad*8];
      Oacc[ct] = MFMA_BF16(pA0, v0, Oacc[ct]);
      Oacc[ct] = MFMA_BF16(pA1, v1, Oacc[ct]);
    }

    if (k0 < SQ - 64) band(k0 + 64 - a0 - 1);   // next iter's 64 new ring cols
  }

  // ---- epilogue: O = Oacc / l, l broadcast from l15==0 lane of own quad ----
#pragma unroll
  for (int r = 0; r < 4; ++r) {
    float l   = __shfl(Oacc[4][r], lane & 48);
    float inv = 1.0f / l;
    const size_t rowo = (size_t)n * SQ * HD + (size_t)(a0 + iiB + r) * HD;
#pragma unroll
    for (int ct = 0; ct < 4; ++ct)
      O[rowo + 16*ct + l15] = Oacc[ct][r] * inv;
  }
}

// ---------------- fallback (R3-style, raw inputs) for small ws ----------------

__global__ __launch_bounds__(256, 4) void relpos_sdpa_fb(
    const float* __restrict__ Q, const float* __restrict__ K,
    const float* __restrict__ V, const float* __restrict__ Ub,
    const float* __restrict__ Vb, const float* __restrict__ R,
    float* __restrict__ O)
{
  const int n    = blockIdx.x;
  const int h    = n & (NHD - 1);
  const int a0   = blockIdx.y * 64;
  const int tid  = threadIdx.x;
  const int lane = tid & 63, wave = tid >> 6;
  const int l15  = lane & 15, quad = lane >> 4;

  const float* Qn = Q + (size_t)n * SQ * HD;
  const float* Kn = K + (size_t)n * SQ * HD;
  const float* Vn = V + (size_t)n * SQ * HD;
  const float* Rh = R + (size_t)h * RMAX * HD;

  __shared__ __align__(16) char lds[38656];
  _Float16* Kb = (_Float16*)lds;
  short*    Ps = (short*)lds;
  short*    Vt = (short*)(lds + 9216);
  _Float16* Pb = (_Float16*)(lds + 9216 + 11520);

  f16x8 quF[2], qvF[5][2];
#pragma unroll
  for (int ks = 0; ks < 2; ++ks) {
    const int db = ks * 32 + quad * 8;
    float ub[8], vb[8];
#pragma unroll
    for (int j = 0; j < 8; ++j) { ub[j] = Ub[h*HD + db + j]; vb[j] = Vb[h*HD + db + j]; }
    {
      const float* p = Qn + (size_t)(a0 + 16*wave + l15) * HD + db;
      f16x8 f;
#pragma unroll
      for (int j = 0; j < 8; ++j) f[j] = (_Float16)(p[j] * 0.125f + ub[j]);
      quF[ks] = f;
    }
#pragma unroll
    for (int rt = 0; rt < 5; ++rt) {
      int row = a0 + 16*rt + l15; if (row > SQ-1) row = SQ-1;
      const float* p = Qn + (size_t)row * HD + db;
      f16x8 f;
#pragma unroll
      for (int j = 0; j < 8; ++j) f[j] = (_Float16)(p[j] * 0.125f + vb[j]);
      qvF[rt][ks] = f;
    }
  }

  if (tid < 64) Vt[64*72 + tid] = (short)0x3F80;

  f32x4 Oacc[5];
#pragma unroll
  for (int ct = 0; ct < 5; ++ct) Oacc[ct] = (f32x4){0.f, 0.f, 0.f, 0.f};

  auto band = [&](int jstart) {
    const int c    = jstart + 16*wave + l15;
    const int j    = (c + 2048) & (SQ - 1);
    const int slot = (c + 2048) & 127;
    const float* rp = Rh + (size_t)j * HD + quad * 8;
    f16x8 B0, B1;
    {
      float4 x0 = *(const float4*)(rp),      x1 = *(const float4*)(rp + 4);
      float4 y0 = *(const float4*)(rp + 32), y1 = *(const float4*)(rp + 36);
#pragma unroll
      for (int t = 0; t < 4; ++t) { B0[t] = (_Float16)(&x0.x)[t]; B0[t+4] = (_Float16)(&x1.x)[t]; }
#pragma unroll
      for (int t = 0; t < 4; ++t) { B1[t] = (_Float16)(&y0.x)[t]; B1[t+4] = (_Float16)(&y1.x)[t]; }
    }
#pragma unroll
    for (int rt = 0; rt < 5; ++rt) {
      f32x4 acc = (f32x4){0.f, 0.f, 0.f, 0.f};
      acc = MFMA_F16(qvF[rt][0], B0, acc);
      acc = MFMA_F16(qvF[rt][1], B1, acc);
      const int row = 16*rt + 4*quad;
      if (rt < 4) {
        *(unsigned*)&Pb[slot*70 + row]     = pkh(acc[0], acc[1]);
        *(unsigned*)&Pb[slot*70 + row + 2] = pkh(acc[2], acc[3]);
      } else if (quad == 0) {
        *(unsigned*)&Pb[slot*70 + row]     = pkh(acc[0], acc[1]);
      }
    }
  };

  band(-a0 - 65);
  band(-a0 - 1);

  const int sr = tid >> 2, sc4 = tid & 3;
  const int iiB = 16*wave + 4*quad;

  for (int k0 = 0; k0 < SQ; k0 += 64) {
    __syncthreads();
    {
      const float* src = Kn + (size_t)(k0 + sr) * HD + sc4 * 16;
      float4 x0 = *(const float4*)(src),     x1 = *(const float4*)(src + 4);
      float4 y0 = *(const float4*)(src + 8), y1 = *(const float4*)(src + 12);
      f16x8 lo, hi;
#pragma unroll
      for (int t = 0; t < 4; ++t) { lo[t] = (_Float16)(&x0.x)[t]; lo[t+4] = (_Float16)(&x1.x)[t]; }
#pragma unroll
      for (int t = 0; t < 4; ++t) { hi[t] = (_Float16)(&y0.x)[t]; hi[t+4] = (_Float16)(&y1.x)[t]; }
      *(f16x8*)&Kb[sr*72 + sc4*16]     = lo;
      *(f16x8*)&Kb[sr*72 + sc4*16 + 8] = hi;
    }
    {
      const int g = lane >> 3;
#pragma unroll
      for (int i = 0; i < 8; ++i) {
        int bp = 8*wave + (i ^ g);
        float v0 = Vn[(size_t)(k0 + 2*bp)     * HD + lane];
        float v1 = Vn[(size_t)(k0 + 2*bp + 1) * HD + lane];
        *(unsigned*)&Vt[lane*72 + 2*bp] = pkb(v0, v1);
      }
    }
    __syncthreads();

    f32x4 sc[4];
#pragma unroll
    for (int ct = 0; ct < 4; ++ct) {
      f16x8 b0 = *(const f16x8*)&Kb[(16*ct + l15)*72 + quad*8];
      f16x8 b1 = *(const f16x8*)&Kb[(16*ct + l15)*72 + 32 + quad*8];
      f32x4 acc = (f32x4){0.f, 0.f, 0.f, 0.f};
      acc = MFMA_F16(quF[0], b0, acc);
      acc = MFMA_F16(quF[1], b1, acc);
      sc[ct] = acc;
    }

    const int dlt = k0 - a0;
#pragma unroll
    for (int r = 0; r < 4; ++r) {
      const int ii = iiB + r;
#pragma unroll
      for (int ct = 0; ct < 4; ++ct) {
        const int e    = dlt + 16*ct + l15 - ii;
        const int u    = (e > 0) ? 1 : 0;
        const int slot = (e - 1 - u + 2048) & 127;
        float pos = (float)Pb[slot*70 + ii + u];
        float s   = sc[ct][r] + ((e == 1) ? 0.f : pos);
        sc[ct][r] = __expf(s - 40.0f);
      }
    }
    __syncthreads();

#pragma unroll
    for (int r = 0; r < 4; ++r)
#pragma unroll
      for (int ct = 0; ct < 4; ++ct)
        Ps[(iiB + r)*68 + 16*ct + l15] = f2b(sc[ct][r]);

    b16x8 pA0 = *(const b16x8*)&Ps[(16*wave + l15)*68 + quad*8];
    b16x8 pA1 = *(const b16x8*)&Ps[(16*wave + l15)*68 + 32 + quad*8];
#pragma unroll
    for (int ct = 0; ct < 5; ++ct) {
      b16x8 v0 = *(const b16x8*)&Vt[(16*ct + l15)*72 + quad*8];
      b16x8 v1 = *(const b16x8*)&Vt[(16*ct + l15)*72 + 32 + quad*8];
      Oacc[ct] = MFMA_BF16(pA0, v0, Oacc[ct]);
      Oacc[ct] = MFMA_BF16(pA1, v1, Oacc[ct]);
    }

    if (k0 < SQ - 64) band(k0 + 64 - a0 - 1);
  }

#pragma unroll
  for (int r = 0; r < 4; ++r) {
    float l   = __shfl(Oacc[4][r], lane & 48);
    float inv = 1.0f / l;
    const size_t rowo = (size_t)n * SQ * HD + (size_t)(a0 + iiB + r) * HD;
#pragma unroll
    for (int ct = 0; ct < 4; ++ct)
      O[rowo + 16*ct + l15] = Oacc[ct][r] * inv;
  }
}

extern "C" void kernel_launch(void* const* d_in, const int* in_sizes, int n_in,
                              void* d_out, int out_size, void* d_ws, size_t ws_size,
                              hipStream_t stream) {
  const float* Q  = (const float*)d_in[0];
  const float* K  = (const float*)d_in[1];
  const float* V  = (const float*)d_in[2];
  const float* Ub = (const float*)d_in[3];  // (1,16,1,64)
  const float* Vb = (const float*)d_in[4];
  const float* R  = (const float*)d_in[5];  // (16,2048,64)
  float* O = (float*)d_out;

  if (ws_size >= WS_NEED) {
    _Float16* Kh  = (_Float16*)((char*)d_ws + KH_OFF);
    short*    Vt  = (short*)((char*)d_ws + VT_OFF);
    _Float16* R16 = (_Float16*)((char*)d_ws + R16_OFF);

    preprep<<<6144, 256, 0, stream>>>(K, R, V, Kh, R16, Vt);

    dim3 grid(64, 16);   // x = n (XCD locality), y = q-tile
    relpos_sdpa_r7<<<grid, 256, 0, stream>>>(Q, Kh, Vt, R16, Ub, Vb, O);
  } else {
    dim3 grid(64, 16);
    relpos_sdpa_fb<<<grid, 256, 0, stream>>>(Q, K, V, Ub, Vb, R, O);
  }
}